// Round 1
// baseline (264.062 us; speedup 1.0000x reference)
//
#include <hip/hip_runtime.h>

#define IN_F   4096
#define OUT_F  11008
#define BATCH  16
#define CO     16             // output channels per block (4 waves x 4 rows)
#define BLOCK  256
#define SPLITK 4
#define KCHUNK (IN_F / SPLITK)   // 1024 k per block
#define NIT    (KCHUNK / 256)    // 4 inner its; wave covers 256 k per it

typedef int   i32x4 __attribute__((ext_vector_type(4)));

// out[b][o] = bias[o]  (pre-init so main kernel can atomicAdd partials)
__global__ __launch_bounds__(BLOCK) void init_out_kernel(
    const float* __restrict__ bias, float* __restrict__ out)
{
    int idx = blockIdx.x * BLOCK + threadIdx.x;
    if (idx < BATCH * OUT_F) {
        int o = idx % OUT_F;
        out[idx] = bias[o];
    }
}

// Block (bx, by): 16 output channels [bx*16 .. bx*16+16), K-chunk by*1024.
// Wave ty owns rows o0..o0+3. Lane tx covers k = {tx*4..tx*4+3} + 256*it.
//
// Round-0 restructure: the K loop previously had a __syncthreads() pair per
// 512-k stage; each barrier drains vmcnt(0), which also drains the weight
// nontemporal-load queue -> the 180 MB weight stream (the only mandatory HBM
// traffic, floor ~29 us) stalled twice per block at 2 waves/SIMD occupancy.
// Now: stage the whole 64 KB x-chunk once (ONE barrier per block), then issue
// the block's entire weight stream (16 x i32x4 per lane, 256 B in flight)
// before any compute. First consumer waits at vmcnt(12), never vmcnt(0).
__global__ __launch_bounds__(BLOCK) void qlin_kernel(
    const float* __restrict__ x,      // [16, 4096]
    const int*   __restrict__ w,      // [11008, 4096] int8 values in int32
    const float* __restrict__ scale,  // [11008]
    float* __restrict__ out)          // [16, 11008], pre-filled with bias
{
    __shared__ float xs[BATCH][KCHUNK];   // 64 KB -> 2 blocks/CU (matches VGPR cap)

    const int tid = threadIdx.x;
    const int tx  = tid & 63;
    const int ty  = tid >> 6;
    const int o0  = blockIdx.x * CO + ty * 4;
    const int kb  = blockIdx.y * KCHUNK;

    const i32x4* __restrict__ wbase = (const i32x4*)(w + (size_t)o0 * IN_F);

    float acc[64];
    #pragma unroll
    for (int i = 0; i < 64; ++i) acc[i] = 0.f;

    // ---- stage full x chunk [16][1024] via async global->LDS, 16B/lane ----
    // f = float4 slot; LDS byte addr = f*16 = wave-uniform + lane*16 (linear).
    #pragma unroll
    for (int j = 0; j < (BATCH * KCHUNK / 4) / BLOCK; ++j) {   // 16 per thread
        int f  = tid + j * BLOCK;
        int b  = f >> 8;                  // KCHUNK/4 = 256 float4 per row
        int kc = f & 255;
        const float* src = x + (size_t)b * IN_F + kb + kc * 4;
        void* dst = (char*)&xs[0][0] + (size_t)f * 16;
        __builtin_amdgcn_global_load_lds(
            (const __attribute__((address_space(1))) void*)src,
            (__attribute__((address_space(3))) void*)dst,
            16, 0, 0);
    }
    __syncthreads();   // the ONLY barrier: x tile resident, vmcnt drained once

    // ---- issue the block's entire weight stream up front ----
    // 16 independent 16B loads/lane; weights are stream-once -> nontemporal.
    i32x4 wr[NIT][4];
    #pragma unroll
    for (int it = 0; it < NIT; ++it) {
        const size_t kg4 = (size_t)((kb >> 2) + it * 64 + tx);
        #pragma unroll
        for (int r = 0; r < 4; ++r)
            wr[it][r] = __builtin_nontemporal_load(wbase + kg4 + (size_t)r * (IN_F / 4));
    }

    // ---- barrier-free compute: consume it-by-it while later its stream ----
    #pragma unroll
    for (int it = 0; it < NIT; ++it) {
        const int kl = it * 256 + tx * 4;   // local k

        float wf[4][4];
        #pragma unroll
        for (int r = 0; r < 4; ++r)
            #pragma unroll
            for (int e = 0; e < 4; ++e)
                wf[r][e] = (float)wr[it][r][e];

        // batches in chunks of 4 to bound live float4 registers
        #pragma unroll
        for (int bc = 0; bc < 4; ++bc) {
            float4 xv[4];
            #pragma unroll
            for (int bb = 0; bb < 4; ++bb)
                xv[bb] = *(const float4*)&xs[bc * 4 + bb][kl];

            #pragma unroll
            for (int r = 0; r < 4; ++r)
                #pragma unroll
                for (int bb = 0; bb < 4; ++bb) {
                    float a = acc[r * 16 + bc * 4 + bb];
                    a += wf[r][0] * xv[bb].x;
                    a += wf[r][1] * xv[bb].y;
                    a += wf[r][2] * xv[bb].z;
                    a += wf[r][3] * xv[bb].w;
                    acc[r * 16 + bc * 4 + bb] = a;
                }
        }
    }

    // ---- in-place folding butterfly across 64 lanes ----
    // After folding, lane tx holds the full partial for flat index tx = r*16+b.
    #pragma unroll
    for (int wd = 32; wd >= 1; wd >>= 1) {
        const bool upper = (tx & wd) != 0;
        #pragma unroll
        for (int i = 0; i < wd; ++i) {
            float lo = acc[i]      + __shfl_xor(acc[i],      wd);
            float hi = acc[i + wd] + __shfl_xor(acc[i + wd], wd);
            acc[i] = upper ? hi : lo;
        }
    }

    const int o = o0 + (tx >> 4);
    const int b = tx & 15;
    atomicAdd(&out[(size_t)b * OUT_F + o], acc[0] * scale[o]);
}

extern "C" void kernel_launch(void* const* d_in, const int* in_sizes, int n_in,
                              void* d_out, int out_size, void* d_ws, size_t ws_size,
                              hipStream_t stream) {
    const float* x     = (const float*)d_in[0];
    const int*   w     = (const int*)d_in[1];
    const float* scale = (const float*)d_in[2];
    const float* bias  = (const float*)d_in[3];
    float* out = (float*)d_out;

    init_out_kernel<<<(BATCH * OUT_F + BLOCK - 1) / BLOCK, BLOCK, 0, stream>>>(bias, out);

    dim3 grid(OUT_F / CO, SPLITK);   // 688 x 4 = 2752 blocks
    qlin_kernel<<<grid, dim3(BLOCK), 0, stream>>>(x, w, scale, out);
}